// Round 4
// baseline (445.068 us; speedup 1.0000x reference)
//
#include <hip/hip_runtime.h>
#include <math.h>

// Problem constants
constexpr int ROWS  = 19456;   // B*C*N = 16*19*64
constexpr int IN_DIM = 200;
constexpr int FREQ  = 101;     // rfft bins
constexpr int VQD   = 64;
constexpr int NEMB  = 8192;

typedef __attribute__((ext_vector_type(8))) short short8;   // 8 bf16 = 4 VGPRs
typedef __attribute__((ext_vector_type(4))) float floatx4;

__device__ __forceinline__ unsigned short f2bf(float v) {   // RTN-even fp32->bf16
    unsigned int u = __builtin_bit_cast(unsigned int, v);
    unsigned int r = u + 0x7fffu + ((u >> 16) & 1u);
    return (unsigned short)(r >> 16);
}
__device__ __forceinline__ float bf2f(unsigned short b) {
    unsigned int u = ((unsigned int)b) << 16;
    return __builtin_bit_cast(float, u);
}

// ---------------- workspace layout ----------------
constexpr size_t align256(size_t x) { return (x + 255) & ~(size_t)255; }
constexpr size_t SZ_TAB = (size_t)IN_DIM * sizeof(double);                   // 200 doubles
constexpr size_t OFF_COS  = 0;
constexpr size_t OFF_SIN  = align256(OFF_COS + SZ_TAB);
constexpr size_t SZ_FB    = (size_t)2 * ROWS * VQD * sizeof(unsigned short); // bf16 feats [2][ROWS][64]
constexpr size_t OFF_FTH  = align256(OFF_SIN + SZ_TAB);
constexpr size_t OFF_FTL  = align256(OFF_FTH + SZ_FB);
constexpr size_t SZ_CBB   = (size_t)2 * NEMB * VQD * sizeof(unsigned short); // bf16 codes [2][8192][64]
constexpr size_t OFF_CBH  = align256(OFF_FTL + SZ_FB);
constexpr size_t OFF_CBL  = align256(OFF_CBH + SZ_CBB);
constexpr size_t SZ_FD    = (size_t)2 * ROWS * VQD * sizeof(double);         // f64 feats
constexpr size_t OFF_FD   = align256(OFF_CBL + SZ_CBB);
constexpr size_t SZ_PI    = (size_t)2 * 4 * ROWS * sizeof(int);
constexpr size_t OFF_PI1  = align256(OFF_FD + SZ_FD);
constexpr size_t OFF_PI2  = align256(OFF_PI1 + SZ_PI);

// ---------------- 1. twiddle table: cos/sin(-2*pi*r/200), r=0..199 ----------------
__global__ void twiddle_kernel(double* __restrict__ cosT, double* __restrict__ sinT) {
    int r = blockIdx.x * 256 + threadIdx.x;
    if (r >= IN_DIM) return;
    double cv, sv;
    if (r == 0)        { cv =  1.0; sv =  0.0; }
    else if (r == 50)  { cv =  0.0; sv = -1.0; }
    else if (r == 100) { cv = -1.0; sv =  0.0; }
    else if (r == 150) { cv =  0.0; sv =  1.0; }
    else {
        double ang = -6.283185307179586476925286766559 * (double)r / (double)IN_DIM;
        cv = cos(ang); sv = sin(ang);
    }
    cosT[r] = cv; sinT[r] = sv;
}

// ---------------- 2. DFT + amp/phase + projection (f64), 8 rows per block ----------------
// Twiddles via per-lane complex rotation recurrence (no LDS gather).
// Exactness: for k=0 and k=100, ws stays a signed zero and im accumulates to exactly +0
// (RN: +0 + (+/-0) = +0), so atan2(+0, re<0) = +pi matches numpy. Elsewhere the ~2e-14
// recurrence drift is far below decision margins (f64 rescore re-adjudicates anyway).
__global__ __launch_bounds__(128, 4) void dft_proj_kernel(
    const float* __restrict__ x, const float* __restrict__ projA, const float* __restrict__ projP,
    const double* __restrict__ cosTG, const double* __restrict__ sinTG,
    unsigned short* __restrict__ ftH, unsigned short* __restrict__ ftL, double* __restrict__ featD)
{
    __shared__ __align__(16) float  xsT[IN_DIM * 8];      // [n][r]  6.4 KB
    __shared__ double ampL[8 * FREQ];                     // [r][k]  6.5 KB
    __shared__ double phL [8 * FREQ];                     //         6.5 KB
    const int tid = threadIdx.x;
    const int r0 = blockIdx.x * 8;

    for (int e = tid; e < 8 * IN_DIM; e += 128) {
        int r = e / IN_DIM, n = e - r * IN_DIM;
        xsT[n * 8 + r] = x[(size_t)(r0 + r) * IN_DIM + n];
    }
    __syncthreads();

    const int k = tid;
    if (k < FREQ) {
        const double c1 = cosTG[k];
        const double s1 = sinTG[k];
        double wc = 1.0, ws = 0.0;
        double re[8], im[8];
#pragma unroll
        for (int r = 0; r < 8; ++r) { re[r] = 0.0; im[r] = 0.0; }

        for (int n = 0; n < IN_DIM; ++n) {
            const float4* xp = (const float4*)(xsT + n * 8);
            float4 x0 = xp[0], x1 = xp[1];
            float xv[8] = {x0.x, x0.y, x0.z, x0.w, x1.x, x1.y, x1.z, x1.w};
#pragma unroll
            for (int r = 0; r < 8; ++r) {
                double xd = (double)xv[r];
                re[r] = fma(xd, wc, re[r]);
                im[r] = fma(xd, ws, im[r]);
            }
            double nwc = wc * c1 - ws * s1;
            double nws = wc * s1 + ws * c1;
            wc = nwc; ws = nws;
        }
#pragma unroll
        for (int r = 0; r < 8; ++r) {
            ampL[r * FREQ + k] = sqrt(re[r] * re[r] + im[r] * im[r]);
            phL [r * FREQ + k] = atan2(im[r], re[r]);
        }
    }
    __syncthreads();

    // projection: lanes 0..63 -> amp, 64..127 -> phase (identical to validated code)
    const int d = tid & 63, which = tid >> 6;
    const float*  proj = which ? projP : projA;
    const double* src  = which ? phL : ampL;
    double acc[8];
#pragma unroll
    for (int r = 0; r < 8; ++r) acc[r] = 0.0;
    for (int kk = 0; kk < FREQ; ++kk) {
        double p = (double)proj[kk * VQD + d];
#pragma unroll
        for (int r = 0; r < 8; ++r) acc[r] += src[r * FREQ + kk] * p;
    }
#pragma unroll
    for (int r = 0; r < 8; ++r) {
        size_t rowi = (size_t)which * ROWS + r0 + r;
        float vf = (float)acc[r];
        unsigned short hb = f2bf(vf);
        unsigned short lb = f2bf(vf - bf2f(hb));
        ftH[rowi * VQD + d] = hb;
        ftL[rowi * VQD + d] = lb;
        featD[rowi * VQD + d] = acc[r];
    }
}

// ---------------- 3. codebook: fold 1/||cb|| (f64 norm) + bf16 hi/lo split ----------------
__global__ __launch_bounds__(256) void cb_prep_kernel(
    const float* __restrict__ cbA, const float* __restrict__ cbP,
    unsigned short* __restrict__ cbH, unsigned short* __restrict__ cbL)
{
    __shared__ float tile[64 * 65];
    __shared__ float inv[64];
    const int tid = threadIdx.x;
    const int which = blockIdx.y;
    const int m0 = blockIdx.x * 64;
    const float* cb = which ? cbP : cbA;
    for (int e = tid; e < 4096; e += 256) {
        int c = e >> 6, d = e & 63;
        tile[c * 65 + d] = cb[(size_t)(m0 + c) * VQD + d];
    }
    __syncthreads();
    if (tid < 64) {
        double s = 0.0;
        for (int d2 = 0; d2 < 64; ++d2) { double v = (double)tile[tid * 65 + d2]; s += v * v; }
        inv[tid] = (float)(1.0 / sqrt(s));
    }
    __syncthreads();
    for (int e = tid; e < 4096; e += 256) {
        int c = e >> 6, d = e & 63;
        float v = tile[c * 65 + d] * inv[c];
        unsigned short hb = f2bf(v);
        unsigned short lb = f2bf(v - bf2f(hb));
        size_t o = ((size_t)which * NEMB + m0 + c) * VQD + d;
        cbH[o] = hb; cbL[o] = lb;
    }
}

// ---------------- 4. bf16x3 MFMA sim + pooled top-2 ----------------
// grid (152, 2, 4): 128 rows x 2048 codes per block; 4 waves, each wave 32 rows.
// Pool-4 across nt tiles (codes 16 apart) before the top-2 insert: 17 VALU ops / 4 values.
// Safety: losing the true 2nd requires 1st&2nd pooled together (p~3/8191/row) AND a
// <4e-6 approx flip -> negligible; f64 rescore adjudicates the surviving 8 candidates.
#define MFMA(a, b, c) __builtin_amdgcn_mfma_f32_16x16x32_bf16(a, b, c, 0, 0, 0)

#define POOL4(va, vb, vc, vd, s, ib) do { \
    float _a = (va), _b = (vb), _c = (vc), _d = (vd); \
    float _mab = fmaxf(_a, _b); int _iab = (_a >= _b) ? (ib) : (ib) + 16; \
    float _mcd = fmaxf(_c, _d); int _icd = (_c >= _d) ? (ib) + 32 : (ib) + 48; \
    float _m = fmaxf(_mab, _mcd); int _pi = (_mab >= _mcd) ? _iab : _icd; \
    bool _c1 = _m > b1v[s]; bool _c2 = _m > b2v[s]; \
    b2v[s] = fmaxf(b2v[s], fminf(b1v[s], _m)); \
    b1v[s] = fmaxf(b1v[s], _m); \
    b2i[s] = _c1 ? b1i[s] : (_c2 ? _pi : b2i[s]); \
    b1i[s] = _c1 ? _pi : b1i[s]; \
} while (0)

__global__ __launch_bounds__(256, 4) void argmax_kernel(
    const unsigned short* __restrict__ ftH, const unsigned short* __restrict__ ftL,
    const unsigned short* __restrict__ cbH, const unsigned short* __restrict__ cbL,
    int* __restrict__ pi1, int* __restrict__ pi2)
{
    __shared__ __align__(16) char lds[2 * 128 * 144];     // 36864 B -> 4 blocks/CU
    const int tid = threadIdx.x;
    const int f = blockIdx.y, z = blockIdx.z;
    const int r0 = blockIdx.x * 128;
    const int w = tid >> 6, lane = tid & 63;
    const int q = lane >> 4, cl = lane & 15;

    const unsigned short* ftHb = ftH + (size_t)f * ROWS * VQD;
    const unsigned short* ftLb = ftL + (size_t)f * ROWS * VQD;
    const unsigned short* cbHb = cbH + (size_t)f * NEMB * VQD;
    const unsigned short* cbLb = cbL + (size_t)f * NEMB * VQD;

    // A fragments: rows r0 + w*32 + {cl, 16+cl}; per-lane k = kb*32 + q*8 .. +8
    short8 aH00, aH01, aH10, aH11, aL00, aL01, aL10, aL11;
    {
        const size_t baseA = (size_t)(r0 + w * 32 + cl) * VQD + q * 8;
        const size_t baseB = baseA + (size_t)16 * VQD;
        aH00 = *(const short8*)(ftHb + baseA);
        aH01 = *(const short8*)(ftHb + baseA + 32);
        aH10 = *(const short8*)(ftHb + baseB);
        aH11 = *(const short8*)(ftHb + baseB + 32);
        aL00 = *(const short8*)(ftLb + baseA);
        aL01 = *(const short8*)(ftLb + baseA + 32);
        aL10 = *(const short8*)(ftLb + baseB);
        aL11 = *(const short8*)(ftLb + baseB + 32);
    }

    float b1v[8], b2v[8]; int b1i[8], b2i[8];
#pragma unroll
    for (int s = 0; s < 8; ++s) { b1v[s] = -INFINITY; b2v[s] = -INFINITY; b1i[s] = 0; b2i[s] = 0; }

    const int cstage = tid >> 1, hstage = tid & 1;
    const size_t gsoff = (size_t)(z * 2048) * VQD;

    for (int it = 0; it < 16; ++it) {
        __syncthreads();
        {   // stage 128 codes (hi+lo): thread -> (code=tid>>1, 32-elem half=tid&1)
            const unsigned short* sH = cbHb + gsoff + (size_t)(it * 128 + cstage) * VQD + hstage * 32;
            const unsigned short* sL = cbLb + gsoff + (size_t)(it * 128 + cstage) * VQD + hstage * 32;
            char* dH = lds + cstage * 144 + hstage * 64;
            char* dL = dH + 128 * 144;
            floatx4 h0 = ((const floatx4*)sH)[0], h1 = ((const floatx4*)sH)[1];
            floatx4 h2 = ((const floatx4*)sH)[2], h3 = ((const floatx4*)sH)[3];
            floatx4 l0 = ((const floatx4*)sL)[0], l1 = ((const floatx4*)sL)[1];
            floatx4 l2 = ((const floatx4*)sL)[2], l3 = ((const floatx4*)sL)[3];
            ((floatx4*)dH)[0] = h0; ((floatx4*)dH)[1] = h1; ((floatx4*)dH)[2] = h2; ((floatx4*)dH)[3] = h3;
            ((floatx4*)dL)[0] = l0; ((floatx4*)dL)[1] = l1; ((floatx4*)dL)[2] = l2; ((floatx4*)dL)[3] = l3;
        }
        __syncthreads();

        const int cbase = z * 2048 + it * 128;
#pragma unroll
        for (int g = 0; g < 2; ++g) {
            floatx4 p0[4], p1[4];
#pragma unroll
            for (int t = 0; t < 4; ++t) {
                const int nt = g * 4 + t;
                const char* pB = lds + (nt * 16 + cl) * 144 + q * 16;
                short8 bH0 = *(const short8*)(pB);
                short8 bH1 = *(const short8*)(pB + 64);
                short8 bL0 = *(const short8*)(pB + 128 * 144);
                short8 bL1 = *(const short8*)(pB + 128 * 144 + 64);

                floatx4 acc0 = {0.f, 0.f, 0.f, 0.f};
                floatx4 acc1 = {0.f, 0.f, 0.f, 0.f};
                acc0 = MFMA(aH00, bH0, acc0);  acc1 = MFMA(aH10, bH0, acc1);
                acc0 = MFMA(aH01, bH1, acc0);  acc1 = MFMA(aH11, bH1, acc1);
                acc0 = MFMA(aH00, bL0, acc0);  acc1 = MFMA(aH10, bL0, acc1);
                acc0 = MFMA(aH01, bL1, acc0);  acc1 = MFMA(aH11, bL1, acc1);
                acc0 = MFMA(aL00, bH0, acc0);  acc1 = MFMA(aL10, bH0, acc1);
                acc0 = MFMA(aL01, bH1, acc0);  acc1 = MFMA(aL11, bH1, acc1);
                p0[t] = acc0; p1[t] = acc1;
            }
            const int ib = cbase + g * 64 + cl;
#pragma unroll
            for (int i = 0; i < 4; ++i) {
                POOL4(p0[0][i], p0[1][i], p0[2][i], p0[3][i], i,     ib);
                POOL4(p1[0][i], p1[1][i], p1[2][i], p1[3][i], 4 + i, ib);
            }
        }
    }

    // block reduction: per-lane top-2 (col-slice cl) -> per-row top-2 of 2048
    __syncthreads();
    float* redv = (float*)lds;
    int*   redi = (int*)(lds + 128 * 33 * 4);
#pragma unroll
    for (int s = 0; s < 8; ++s) {
        int rowl = w * 32 + ((s & 4) << 2) + q * 4 + (s & 3);   // +16 when s>=4
        int base = rowl * 33 + cl * 2;
        redv[base]     = b1v[s]; redi[base]     = b1i[s];
        redv[base + 1] = b2v[s]; redi[base + 1] = b2i[s];
    }
    __syncthreads();
    if (tid < 128) {
        float v1 = -INFINITY, v2 = -INFINITY; int i1 = 0x7fffffff, i2 = 0x7fffffff;
        for (int e = 0; e < 32; ++e) {
            float v = redv[tid * 33 + e]; int id = redi[tid * 33 + e];
            if (v > v1 || (v == v1 && id < i1)) { v2 = v1; i2 = i1; v1 = v; i1 = id; }
            else if (v > v2 || (v == v2 && id < i2)) { v2 = v; i2 = id; }
        }
        size_t p = ((size_t)(f * 4 + z)) * ROWS + r0 + tid;
        pi1[p] = i1; pi2[p] = i2;
    }
}

// ---------------- 5. f64 rescore of the 8 candidates/row, emit int32 index ----------------
__global__ __launch_bounds__(256) void rescore_kernel(
    const double* __restrict__ featD,
    const float* __restrict__ cbA, const float* __restrict__ cbP,
    const int* __restrict__ pi1, const int* __restrict__ pi2,
    int* __restrict__ out)
{
    const int tid = threadIdx.x;
    const int lane = tid & 63, wave = tid >> 6;
    const int task = blockIdx.x * 4 + wave;           // 0 .. 2*ROWS-1
    const int f = task / ROWS;
    const int row = task - f * ROWS;
    const float* cb = f ? cbP : cbA;
    const double fd = featD[((size_t)f * ROWS + row) * VQD + lane];
    double bestv = -1.0e300; int besti = 0x7fffffff;
    for (int c = 0; c < 8; ++c) {
        int z = c >> 1;
        size_t p = ((size_t)(f * 4 + z)) * ROWS + row;
        int idx = (c & 1) ? pi2[p] : pi1[p];
        double cv = (double)cb[(size_t)idx * VQD + lane];
        double t = fd * cv, s = cv * cv;
        for (int m = 32; m >= 1; m >>= 1) {
            t += __shfl_xor(t, m, 64);
            s += __shfl_xor(s, m, 64);
        }
        double sim = t / sqrt(s);
        if (sim > bestv || (sim == bestv && idx < besti)) { bestv = sim; besti = idx; }
    }
    if (lane == 0) out[task] = besti;
}

// ---------------- launch ----------------
extern "C" void kernel_launch(void* const* d_in, const int* in_sizes, int n_in,
                              void* d_out, int out_size, void* d_ws, size_t ws_size,
                              hipStream_t stream)
{
    const float* x     = (const float*)d_in[0];
    const float* projA = (const float*)d_in[1];
    const float* projP = (const float*)d_in[2];
    const float* cbA   = (const float*)d_in[3];
    const float* cbP   = (const float*)d_in[4];

    char* ws = (char*)d_ws;
    double*         cosT  = (double*)(ws + OFF_COS);
    double*         sinT  = (double*)(ws + OFF_SIN);
    unsigned short* ftH   = (unsigned short*)(ws + OFF_FTH);
    unsigned short* ftL   = (unsigned short*)(ws + OFF_FTL);
    unsigned short* cbHp  = (unsigned short*)(ws + OFF_CBH);
    unsigned short* cbLp  = (unsigned short*)(ws + OFF_CBL);
    double*         featD = (double*)(ws + OFF_FD);
    int*            pi1   = (int*)(ws + OFF_PI1);
    int*            pi2   = (int*)(ws + OFF_PI2);

    twiddle_kernel<<<1, 256, 0, stream>>>(cosT, sinT);
    dft_proj_kernel<<<ROWS / 8, 128, 0, stream>>>(x, projA, projP, cosT, sinT, ftH, ftL, featD);
    cb_prep_kernel<<<dim3(NEMB / 64, 2), 256, 0, stream>>>(cbA, cbP, cbHp, cbLp);
    argmax_kernel<<<dim3(ROWS / 128, 2, 4), 256, 0, stream>>>(ftH, ftL, cbHp, cbLp, pi1, pi2);
    rescore_kernel<<<(2 * ROWS) / 4, 256, 0, stream>>>(featD, cbA, cbP, pi1, pi2, (int*)d_out);
}

// Round 5
// 364.781 us; speedup vs baseline: 1.2201x; 1.2201x over previous
//
#include <hip/hip_runtime.h>
#include <math.h>

// Problem constants
constexpr int ROWS  = 19456;   // B*C*N = 16*19*64
constexpr int IN_DIM = 200;
constexpr int FREQ  = 101;     // rfft bins
constexpr int VQD   = 64;
constexpr int NEMB  = 8192;

typedef __attribute__((ext_vector_type(8))) short short8;   // 8 bf16 = 4 VGPRs
typedef __attribute__((ext_vector_type(4))) float floatx4;

__device__ __forceinline__ unsigned short f2bf(float v) {   // RTN-even fp32->bf16
    unsigned int u = __builtin_bit_cast(unsigned int, v);
    unsigned int r = u + 0x7fffu + ((u >> 16) & 1u);
    return (unsigned short)(r >> 16);
}
__device__ __forceinline__ float bf2f(unsigned short b) {
    unsigned int u = ((unsigned int)b) << 16;
    return __builtin_bit_cast(float, u);
}

// ---------------- workspace layout ----------------
constexpr size_t align256(size_t x) { return (x + 255) & ~(size_t)255; }
constexpr size_t SZ_FB    = (size_t)2 * ROWS * VQD * sizeof(unsigned short); // bf16 feats [2][ROWS][64]
constexpr size_t OFF_FTH  = 0;
constexpr size_t OFF_FTL  = align256(OFF_FTH + SZ_FB);
constexpr size_t SZ_CBB   = (size_t)2 * NEMB * VQD * sizeof(unsigned short); // bf16 codes [2][8192][64]
constexpr size_t OFF_CBH  = align256(OFF_FTL + SZ_FB);
constexpr size_t OFF_CBL  = align256(OFF_CBH + SZ_CBB);
constexpr size_t SZ_FD    = (size_t)2 * ROWS * VQD * sizeof(double);         // f64 feats
constexpr size_t OFF_FD   = align256(OFF_CBL + SZ_CBB);
constexpr size_t SZ_INV   = (size_t)2 * NEMB * sizeof(double);               // f64 1/||cb||
constexpr size_t OFF_INV  = align256(OFF_FD + SZ_FD);
constexpr size_t SZ_PI    = (size_t)2 * 4 * ROWS * sizeof(int);
constexpr size_t OFF_PI1  = align256(OFF_INV + SZ_INV);
constexpr size_t OFF_PI2  = align256(OFF_PI1 + SZ_PI);

// ---------------- 1. DFT + amp/phase + projection (f64), 8 rows per block ----------------
// Per-lane twiddle cis(-2*pi*k/200) computed inline (same libm + exact quarter points as the
// validated table version -> bitwise-identical recurrence). k=0/k=100 keep im = +0 exactly,
// so atan2(+0, re<0) = +pi matches numpy.
__global__ __launch_bounds__(128, 4) void dft_proj_kernel(
    const float* __restrict__ x, const float* __restrict__ projA, const float* __restrict__ projP,
    unsigned short* __restrict__ ftH, unsigned short* __restrict__ ftL, double* __restrict__ featD)
{
    __shared__ __align__(16) float  xsT[IN_DIM * 8];      // [n][r]  6.4 KB
    __shared__ double ampL[8 * FREQ];                     // [r][k]  6.5 KB
    __shared__ double phL [8 * FREQ];                     //         6.5 KB
    const int tid = threadIdx.x;
    const int r0 = blockIdx.x * 8;

    for (int e = tid; e < 8 * IN_DIM; e += 128) {
        int r = e / IN_DIM, n = e - r * IN_DIM;
        xsT[n * 8 + r] = x[(size_t)(r0 + r) * IN_DIM + n];
    }
    __syncthreads();

    const int k = tid;
    if (k < FREQ) {
        double c1, s1;
        if (k == 0)        { c1 =  1.0; s1 =  0.0; }
        else if (k == 50)  { c1 =  0.0; s1 = -1.0; }
        else if (k == 100) { c1 = -1.0; s1 =  0.0; }
        else {
            double ang = -6.283185307179586476925286766559 * (double)k / (double)IN_DIM;
            c1 = cos(ang); s1 = sin(ang);
        }
        double wc = 1.0, ws = 0.0;
        double re[8], im[8];
#pragma unroll
        for (int r = 0; r < 8; ++r) { re[r] = 0.0; im[r] = 0.0; }

        for (int n = 0; n < IN_DIM; ++n) {
            const float4* xp = (const float4*)(xsT + n * 8);
            float4 x0 = xp[0], x1 = xp[1];
            float xv[8] = {x0.x, x0.y, x0.z, x0.w, x1.x, x1.y, x1.z, x1.w};
#pragma unroll
            for (int r = 0; r < 8; ++r) {
                double xd = (double)xv[r];
                re[r] = fma(xd, wc, re[r]);
                im[r] = fma(xd, ws, im[r]);
            }
            double nwc = wc * c1 - ws * s1;
            double nws = wc * s1 + ws * c1;
            wc = nwc; ws = nws;
        }
#pragma unroll
        for (int r = 0; r < 8; ++r) {
            ampL[r * FREQ + k] = sqrt(re[r] * re[r] + im[r] * im[r]);
            phL [r * FREQ + k] = atan2(im[r], re[r]);
        }
    }
    __syncthreads();

    // projection: lanes 0..63 -> amp, 64..127 -> phase (identical to validated code)
    const int d = tid & 63, which = tid >> 6;
    const float*  proj = which ? projP : projA;
    const double* src  = which ? phL : ampL;
    double acc[8];
#pragma unroll
    for (int r = 0; r < 8; ++r) acc[r] = 0.0;
    for (int kk = 0; kk < FREQ; ++kk) {
        double p = (double)proj[kk * VQD + d];
#pragma unroll
        for (int r = 0; r < 8; ++r) acc[r] += src[r * FREQ + kk] * p;
    }
#pragma unroll
    for (int r = 0; r < 8; ++r) {
        size_t rowi = (size_t)which * ROWS + r0 + r;
        float vf = (float)acc[r];
        unsigned short hb = f2bf(vf);
        unsigned short lb = f2bf(vf - bf2f(hb));
        ftH[rowi * VQD + d] = hb;
        ftL[rowi * VQD + d] = lb;
        featD[rowi * VQD + d] = acc[r];
    }
}

// ---------------- 2. codebook: fold 1/||cb|| + bf16 hi/lo split + f64 inv-norm ----------------
__global__ __launch_bounds__(256) void cb_prep_kernel(
    const float* __restrict__ cbA, const float* __restrict__ cbP,
    unsigned short* __restrict__ cbH, unsigned short* __restrict__ cbL,
    double* __restrict__ invnD)
{
    __shared__ float tile[64 * 65];
    __shared__ float inv[64];
    const int tid = threadIdx.x;
    const int which = blockIdx.y;
    const int m0 = blockIdx.x * 64;
    const float* cb = which ? cbP : cbA;
    for (int e = tid; e < 4096; e += 256) {
        int c = e >> 6, d = e & 63;
        tile[c * 65 + d] = cb[(size_t)(m0 + c) * VQD + d];
    }
    __syncthreads();
    if (tid < 64) {
        double s = 0.0;
        for (int d2 = 0; d2 < 64; ++d2) { double v = (double)tile[tid * 65 + d2]; s += v * v; }
        inv[tid] = (float)(1.0 / sqrt(s));
        invnD[(size_t)which * NEMB + m0 + tid] = 1.0 / sqrt(s);
    }
    __syncthreads();
    for (int e = tid; e < 4096; e += 256) {
        int c = e >> 6, d = e & 63;
        float v = tile[c * 65 + d] * inv[c];
        unsigned short hb = f2bf(v);
        unsigned short lb = f2bf(v - bf2f(hb));
        size_t o = ((size_t)which * NEMB + m0 + c) * VQD + d;
        cbH[o] = hb; cbL[o] = lb;
    }
}

// ---------------- 3. bf16x3 MFMA sim + inline pool-2 top-2 ----------------
// grid (152, 2, 4): 128 rows x 2048 codes per block; 4 waves, each wave 32 rows.
// Pool-2 across adjacent nt tiles, computed inline (only one extra acc-pair live -> no
// spill, unlike round-4's batch-of-4 arrays which hit scratch for 156 MB of writes).
// Safety: losing the true 2nd needs 1st&2nd pooled together (p~1/8191/row) AND a <4e-6
// approx flip -> negligible; f64 rescore adjudicates the surviving 8 candidates.
#define MFMA(a, b, c) __builtin_amdgcn_mfma_f32_16x16x32_bf16(a, b, c, 0, 0, 0)

#define POOL2(va, vb, s, ib) do { \
    float _a = (va), _b = (vb); \
    float _m = fmaxf(_a, _b); int _pi = (_a >= _b) ? (ib) : (ib) + 16; \
    bool _c1 = _m > b1v[s]; bool _c2 = _m > b2v[s]; \
    b2v[s] = fmaxf(b2v[s], fminf(b1v[s], _m)); \
    b1v[s] = fmaxf(b1v[s], _m); \
    b2i[s] = _c1 ? b1i[s] : (_c2 ? _pi : b2i[s]); \
    b1i[s] = _c1 ? _pi : b1i[s]; \
} while (0)

__global__ __launch_bounds__(256, 3) void argmax_kernel(
    const unsigned short* __restrict__ ftH, const unsigned short* __restrict__ ftL,
    const unsigned short* __restrict__ cbH, const unsigned short* __restrict__ cbL,
    int* __restrict__ pi1, int* __restrict__ pi2)
{
    __shared__ __align__(16) char lds[2 * 128 * 144];     // 36864 B -> 4 blocks/CU by LDS
    const int tid = threadIdx.x;
    const int f = blockIdx.y, z = blockIdx.z;
    const int r0 = blockIdx.x * 128;
    const int w = tid >> 6, lane = tid & 63;
    const int q = lane >> 4, cl = lane & 15;

    const unsigned short* ftHb = ftH + (size_t)f * ROWS * VQD;
    const unsigned short* ftLb = ftL + (size_t)f * ROWS * VQD;
    const unsigned short* cbHb = cbH + (size_t)f * NEMB * VQD;
    const unsigned short* cbLb = cbL + (size_t)f * NEMB * VQD;

    // A fragments: rows r0 + w*32 + {cl, 16+cl}; per-lane k = kb*32 + q*8 .. +8
    short8 aH00, aH01, aH10, aH11, aL00, aL01, aL10, aL11;
    {
        const size_t baseA = (size_t)(r0 + w * 32 + cl) * VQD + q * 8;
        const size_t baseB = baseA + (size_t)16 * VQD;
        aH00 = *(const short8*)(ftHb + baseA);
        aH01 = *(const short8*)(ftHb + baseA + 32);
        aH10 = *(const short8*)(ftHb + baseB);
        aH11 = *(const short8*)(ftHb + baseB + 32);
        aL00 = *(const short8*)(ftLb + baseA);
        aL01 = *(const short8*)(ftLb + baseA + 32);
        aL10 = *(const short8*)(ftLb + baseB);
        aL11 = *(const short8*)(ftLb + baseB + 32);
    }

    float b1v[8], b2v[8]; int b1i[8], b2i[8];
#pragma unroll
    for (int s = 0; s < 8; ++s) { b1v[s] = -INFINITY; b2v[s] = -INFINITY; b1i[s] = 0; b2i[s] = 0; }

    const int cstage = tid >> 1, hstage = tid & 1;
    const size_t gsoff = (size_t)(z * 2048) * VQD;

    for (int it = 0; it < 16; ++it) {
        __syncthreads();
        {   // stage 128 codes (hi+lo): thread -> (code=tid>>1, 32-elem half=tid&1)
            const unsigned short* sH = cbHb + gsoff + (size_t)(it * 128 + cstage) * VQD + hstage * 32;
            const unsigned short* sL = cbLb + gsoff + (size_t)(it * 128 + cstage) * VQD + hstage * 32;
            char* dH = lds + cstage * 144 + hstage * 64;
            char* dL = dH + 128 * 144;
            floatx4 h0 = ((const floatx4*)sH)[0], h1 = ((const floatx4*)sH)[1];
            floatx4 h2 = ((const floatx4*)sH)[2], h3 = ((const floatx4*)sH)[3];
            floatx4 l0 = ((const floatx4*)sL)[0], l1 = ((const floatx4*)sL)[1];
            floatx4 l2 = ((const floatx4*)sL)[2], l3 = ((const floatx4*)sL)[3];
            ((floatx4*)dH)[0] = h0; ((floatx4*)dH)[1] = h1; ((floatx4*)dH)[2] = h2; ((floatx4*)dH)[3] = h3;
            ((floatx4*)dL)[0] = l0; ((floatx4*)dL)[1] = l1; ((floatx4*)dL)[2] = l2; ((floatx4*)dL)[3] = l3;
        }
        __syncthreads();

        const int cbase = z * 2048 + it * 128;
#pragma unroll
        for (int np = 0; np < 4; ++np) {
            // tile pair nt = 2*np, 2*np+1 (codes 16 apart)
            floatx4 pa0, pa1, pb0, pb1;
            {
                const char* pB = lds + ((2 * np) * 16 + cl) * 144 + q * 16;
                short8 bH0 = *(const short8*)(pB);
                short8 bH1 = *(const short8*)(pB + 64);
                short8 bL0 = *(const short8*)(pB + 128 * 144);
                short8 bL1 = *(const short8*)(pB + 128 * 144 + 64);
                floatx4 a0 = {0.f, 0.f, 0.f, 0.f}, a1 = {0.f, 0.f, 0.f, 0.f};
                a0 = MFMA(aH00, bH0, a0);  a1 = MFMA(aH10, bH0, a1);
                a0 = MFMA(aH01, bH1, a0);  a1 = MFMA(aH11, bH1, a1);
                a0 = MFMA(aH00, bL0, a0);  a1 = MFMA(aH10, bL0, a1);
                a0 = MFMA(aH01, bL1, a0);  a1 = MFMA(aH11, bL1, a1);
                a0 = MFMA(aL00, bH0, a0);  a1 = MFMA(aL10, bH0, a1);
                a0 = MFMA(aL01, bH1, a0);  a1 = MFMA(aL11, bH1, a1);
                pa0 = a0; pa1 = a1;
            }
            {
                const char* pB = lds + ((2 * np + 1) * 16 + cl) * 144 + q * 16;
                short8 bH0 = *(const short8*)(pB);
                short8 bH1 = *(const short8*)(pB + 64);
                short8 bL0 = *(const short8*)(pB + 128 * 144);
                short8 bL1 = *(const short8*)(pB + 128 * 144 + 64);
                floatx4 a0 = {0.f, 0.f, 0.f, 0.f}, a1 = {0.f, 0.f, 0.f, 0.f};
                a0 = MFMA(aH00, bH0, a0);  a1 = MFMA(aH10, bH0, a1);
                a0 = MFMA(aH01, bH1, a0);  a1 = MFMA(aH11, bH1, a1);
                a0 = MFMA(aH00, bL0, a0);  a1 = MFMA(aH10, bL0, a1);
                a0 = MFMA(aH01, bL1, a0);  a1 = MFMA(aH11, bL1, a1);
                a0 = MFMA(aL00, bH0, a0);  a1 = MFMA(aL10, bH0, a1);
                a0 = MFMA(aL01, bH1, a0);  a1 = MFMA(aL11, bH1, a1);
                pb0 = a0; pb1 = a1;
            }
            const int ib = cbase + np * 32 + cl;
#pragma unroll
            for (int i = 0; i < 4; ++i) {
                POOL2(pa0[i], pb0[i], i,     ib);
                POOL2(pa1[i], pb1[i], 4 + i, ib);
            }
        }
    }

    // block reduction: per-lane top-2 (col-slice cl) -> per-row top-2 of 2048
    __syncthreads();
    float* redv = (float*)lds;
    int*   redi = (int*)(lds + 128 * 33 * 4);
#pragma unroll
    for (int s = 0; s < 8; ++s) {
        int rowl = w * 32 + ((s & 4) << 2) + q * 4 + (s & 3);   // +16 when s>=4
        int base = rowl * 33 + cl * 2;
        redv[base]     = b1v[s]; redi[base]     = b1i[s];
        redv[base + 1] = b2v[s]; redi[base + 1] = b2i[s];
    }
    __syncthreads();
    if (tid < 128) {
        float v1 = -INFINITY, v2 = -INFINITY; int i1 = 0x7fffffff, i2 = 0x7fffffff;
        for (int e = 0; e < 32; ++e) {
            float v = redv[tid * 33 + e]; int id = redi[tid * 33 + e];
            if (v > v1 || (v == v1 && id < i1)) { v2 = v1; i2 = i1; v1 = v; i1 = id; }
            else if (v > v2 || (v == v2 && id < i2)) { v2 = v; i2 = id; }
        }
        size_t p = ((size_t)(f * 4 + z)) * ROWS + r0 + tid;
        pi1[p] = i1; pi2[p] = i2;
    }
}

// ---------------- 4. f64 rescore of the 8 candidates/row, emit int32 index ----------------
// Prefetch all candidate rows, use precomputed f64 inv-norms (halves the shuffle work).
__global__ __launch_bounds__(256) void rescore_kernel(
    const double* __restrict__ featD, const double* __restrict__ invnD,
    const float* __restrict__ cbA, const float* __restrict__ cbP,
    const int* __restrict__ pi1, const int* __restrict__ pi2,
    int* __restrict__ out)
{
    const int tid = threadIdx.x;
    const int lane = tid & 63, wave = tid >> 6;
    const int task = blockIdx.x * 4 + wave;           // 0 .. 2*ROWS-1
    const int f = task / ROWS;
    const int row = task - f * ROWS;
    const float* cb = f ? cbP : cbA;
    const double fd = featD[((size_t)f * ROWS + row) * VQD + lane];

    int idxs[8];
#pragma unroll
    for (int c = 0; c < 8; ++c) {
        int zz = c >> 1;
        size_t p = ((size_t)(f * 4 + zz)) * ROWS + row;
        idxs[c] = (c & 1) ? pi2[p] : pi1[p];
    }
    double cv[8];
#pragma unroll
    for (int c = 0; c < 8; ++c)
        cv[c] = (double)cb[(size_t)idxs[c] * VQD + lane];

    double bestv = -1.0e300; int besti = 0x7fffffff;
#pragma unroll
    for (int c = 0; c < 8; ++c) {
        double t = fd * cv[c];
        for (int m = 32; m >= 1; m >>= 1) t += __shfl_xor(t, m, 64);
        double sim = t * invnD[(size_t)f * NEMB + idxs[c]];
        int idx = idxs[c];
        if (sim > bestv || (sim == bestv && idx < besti)) { bestv = sim; besti = idx; }
    }
    if (lane == 0) out[task] = besti;
}

// ---------------- launch ----------------
extern "C" void kernel_launch(void* const* d_in, const int* in_sizes, int n_in,
                              void* d_out, int out_size, void* d_ws, size_t ws_size,
                              hipStream_t stream)
{
    const float* x     = (const float*)d_in[0];
    const float* projA = (const float*)d_in[1];
    const float* projP = (const float*)d_in[2];
    const float* cbA   = (const float*)d_in[3];
    const float* cbP   = (const float*)d_in[4];

    char* ws = (char*)d_ws;
    unsigned short* ftH   = (unsigned short*)(ws + OFF_FTH);
    unsigned short* ftL   = (unsigned short*)(ws + OFF_FTL);
    unsigned short* cbHp  = (unsigned short*)(ws + OFF_CBH);
    unsigned short* cbLp  = (unsigned short*)(ws + OFF_CBL);
    double*         featD = (double*)(ws + OFF_FD);
    double*         invnD = (double*)(ws + OFF_INV);
    int*            pi1   = (int*)(ws + OFF_PI1);
    int*            pi2   = (int*)(ws + OFF_PI2);

    dft_proj_kernel<<<ROWS / 8, 128, 0, stream>>>(x, projA, projP, ftH, ftL, featD);
    cb_prep_kernel<<<dim3(NEMB / 64, 2), 256, 0, stream>>>(cbA, cbP, cbHp, cbLp, invnD);
    argmax_kernel<<<dim3(ROWS / 128, 2, 4), 256, 0, stream>>>(ftH, ftL, cbHp, cbLp, pi1, pi2);
    rescore_kernel<<<(2 * ROWS) / 4, 256, 0, stream>>>(featD, invnD, cbA, cbP, pi1, pi2, (int*)d_out);
}